// Round 3
// baseline (218.345 us; speedup 1.0000x reference)
//
#include <hip/hip_runtime.h>

typedef __bf16 bf16;
typedef bf16 bf16x8 __attribute__((ext_vector_type(8)));
typedef float f32x4 __attribute__((ext_vector_type(4)));

#define WREG 19200      // per-wave LDS bytes: 48 T-rows x 400B pitch
// Wave-private everything: each wave owns 16 consecutive points.
//   T rows [0,19200): row = p_local*3 + i  (48 rows = 3 full 16-row MFMA m-tiles)
//   Y stage [0,12288): aliases T after MFMA reads complete (same-wave lgkmcnt order)
// ZERO block barriers. 400B pitch => ds_read_b128 A-frags are 2-way (free).
// LDS 4*19200 = 76800 B -> 2 blocks/CU (8 waves/CU); per-wave ILP replaces TLP.

__device__ __forceinline__ void load4(const float* __restrict__ J, const float* __restrict__ X,
                                      long p0, int lane, float jv[4][6], float xv[4][3])
{
    const float* jg = J + p0 * 384 + lane * 6;   // lane d: its 24B of each point's J
    #pragma unroll
    for (int q = 0; q < 4; ++q) {
        float2 ja  = *(const float2*)(jg + q * 384 + 0);
        float2 jb  = *(const float2*)(jg + q * 384 + 2);
        float2 jc2 = *(const float2*)(jg + q * 384 + 4);
        jv[q][0] = ja.x;  jv[q][1] = ja.y;
        jv[q][2] = jb.x;  jv[q][3] = jb.y;
        jv[q][4] = jc2.x; jv[q][5] = jc2.y;
    }
    const float* xg = X + p0 * 192 + lane * 3;
    #pragma unroll
    for (int q = 0; q < 4; ++q) {
        xv[q][0] = xg[q * 192 + 0];
        xv[q][1] = xg[q * 192 + 1];
        xv[q][2] = xg[q * 192 + 2];
    }
}

__global__ __launch_bounds__(256, 2)
void affine_linear_fused(const float* __restrict__ X, const float* __restrict__ J,
                         const float* __restrict__ A, const float* __restrict__ Bm,
                         const float* __restrict__ C, float* __restrict__ Y)
{
    __shared__ __attribute__((aligned(128))) unsigned char lds[4 * WREG];

    const int tid  = threadIdx.x;
    const int wave = tid >> 6;
    const int lane = tid & 63;
    const int l16  = lane & 15;
    const int lq   = lane >> 4;
    unsigned char* wbase = &lds[wave * WREG];
    const long bn0 = (long)blockIdx.x * 64 + wave * 16;   // wave's first point

    // ---- Terms for 16 points in 4 sub-batches; 1-deep J/X register prefetch ----
    float jc[4][6], xc[4][3];
    load4(J, X, bn0, lane, jc, xc);

    #pragma unroll
    for (int s = 0; s < 4; ++s) {
        float jn[4][6], xn[4][3];
        if (s < 3) load4(J, X, bn0 + (s + 1) * 4, lane, jn, xn);

        #pragma unroll
        for (int q = 0; q < 4; ++q) {
            float a1x = jc[q][0], a2x = jc[q][1];
            float a1y = jc[q][2], a2y = jc[q][3];
            float a1z = jc[q][4], a2z = jc[q][5];
            float xx = xc[q][0], xy = xc[q][1], xz = xc[q][2];

            float n1sq = a1x*a1x + a1y*a1y + a1z*a1z;
            float inv1 = __builtin_amdgcn_rsqf(fmaxf(n1sq, 1e-24f));  // == 1/max(sqrt,1e-12)
            float b1x = a1x*inv1, b1y = a1y*inv1, b1z = a1z*inv1;
            float dot = b1x*a2x + b1y*a2y + b1z*a2z;
            float ux = a2x - dot*b1x, uy = a2y - dot*b1y, uz = a2z - dot*b1z;
            float n2sq = ux*ux + uy*uy + uz*uz;
            float inv2 = __builtin_amdgcn_rsqf(fmaxf(n2sq, 1e-24f));
            float b2x = ux*inv2, b2y = uy*inv2, b2z = uz*inv2;
            float b3x = b1y*b2z - b1z*b2y;
            float b3y = b1z*b2x - b1x*b2z;
            float b3z = b1x*b2y - b1y*b2x;

            float rt0 = b1x*xx + b1y*xy + b1z*xz;
            float rt1 = b2x*xx + b2y*xy + b2z*xz;
            float rt2 = b3x*xx + b3y*xy + b3z*xz;

            float at0 = b1x*rt0 + b2x*rt1;
            float at1 = b1y*rt0 + b2y*rt1;
            float at2 = b1z*rt0 + b2z*rt1;
            float bt0 = b2x*rt0 - b1x*rt1;
            float bt1 = b2y*rt0 - b1y*rt1;
            float bt2 = b2z*rt0 - b1z*rt1;
            float ct0 = b3x*rt2, ct1 = b3y*rt2, ct2 = b3z*rt2;

            const int row = (s * 4 + q) * 3;
            bf16* r0 = (bf16*)(wbase + (row + 0) * 400);
            bf16* r1 = (bf16*)(wbase + (row + 1) * 400);
            bf16* r2 = (bf16*)(wbase + (row + 2) * 400);
            r0[lane] = (bf16)at0; r0[64+lane] = (bf16)bt0; r0[128+lane] = (bf16)ct0;
            r1[lane] = (bf16)at1; r1[64+lane] = (bf16)bt1; r1[128+lane] = (bf16)ct1;
            r2[lane] = (bf16)at2; r2[64+lane] = (bf16)bt2; r2[128+lane] = (bf16)ct2;
        }

        if (s < 3) {
            #pragma unroll
            for (int q = 0; q < 4; ++q) {
                #pragma unroll
                for (int k = 0; k < 6; ++k) jc[q][k] = jn[q][k];
                #pragma unroll
                for (int k = 0; k < 3; ++k) xc[q][k] = xn[q][k];
            }
        }
    }

    // Same-wave RAW through LDS: in-order DS pipe + lgkmcnt. NO block barrier.
    __asm__ volatile("s_waitcnt lgkmcnt(0)" ::: "memory");

    // ---- MFMA: D[m, f] = sum_k T[m,k] * W[f,k], m=48 rows, f=64 cols ----
    const unsigned char* arow[3];
    #pragma unroll
    for (int mt = 0; mt < 3; ++mt)
        arow[mt] = wbase + (mt * 16 + l16) * 400 + lq * 16;

    f32x4 acc[3][4];
    #pragma unroll
    for (int mt = 0; mt < 3; ++mt)
        #pragma unroll
        for (int nt = 0; nt < 4; ++nt)
            acc[mt][nt] = (f32x4){0.f, 0.f, 0.f, 0.f};

    #pragma unroll
    for (int nt = 0; nt < 4; ++nt) {
        const int f = nt * 16 + l16;
        f32x4 wlo[6], whi[6];
        #pragma unroll
        for (int kk = 0; kk < 6; ++kk) {
            const float* src = (kk < 2) ? A : (kk < 4) ? Bm : C;
            const f32x4* p4 = (const f32x4*)(src + f * 64 + (kk & 1) * 32 + lq * 8);
            wlo[kk] = p4[0];
            whi[kk] = p4[1];
        }
        #pragma unroll
        for (int kk = 0; kk < 6; ++kk) {
            bf16x8 w;
            w[0] = (bf16)wlo[kk][0]; w[1] = (bf16)wlo[kk][1];
            w[2] = (bf16)wlo[kk][2]; w[3] = (bf16)wlo[kk][3];
            w[4] = (bf16)whi[kk][0]; w[5] = (bf16)whi[kk][1];
            w[6] = (bf16)whi[kk][2]; w[7] = (bf16)whi[kk][3];
            #pragma unroll
            for (int mt = 0; mt < 3; ++mt) {
                bf16x8 af = *(const bf16x8*)(arow[mt] + kk * 64);
                acc[mt][nt] = __builtin_amdgcn_mfma_f32_16x16x32_bf16(af, w, acc[mt][nt], 0, 0, 0);
            }
        }
    }

    // All A-frag reads complete before aliasing overwrite (same-wave order + wait).
    __asm__ volatile("s_waitcnt lgkmcnt(0)" ::: "memory");

    // ---- Y stage into [0,12288): chunk p = 192 floats (f-major, i inner) ----
    float* yw = (float*)wbase;
    #pragma unroll
    for (int mt = 0; mt < 3; ++mt)
        #pragma unroll
        for (int nt = 0; nt < 4; ++nt)
            #pragma unroll
            for (int r = 0; r < 4; ++r) {
                int m = mt * 16 + lq * 4 + r;   // row = p*3 + i
                int p = m / 3;
                int i = m - p * 3;
                yw[p * 192 + (nt * 16 + l16) * 3 + i] = acc[mt][nt][r];
            }

    __asm__ volatile("s_waitcnt lgkmcnt(0)" ::: "memory");

    // ---- Coalesced writeout: wave's 16 points are 12 KB contiguous in Y ----
    const f32x4* ysrc = (const f32x4*)yw;
    f32x4* ydst = (f32x4*)(Y + bn0 * 192);
    #pragma unroll
    for (int v = 0; v < 12; ++v)
        ydst[v * 64 + lane] = ysrc[v * 64 + lane];
}

extern "C" void kernel_launch(void* const* d_in, const int* in_sizes, int n_in,
                              void* d_out, int out_size, void* d_ws, size_t ws_size,
                              hipStream_t stream) {
    const float* X  = (const float*)d_in[0];
    const float* J  = (const float*)d_in[1];
    const float* A  = (const float*)d_in[2];
    const float* Bm = (const float*)d_in[3];
    const float* C  = (const float*)d_in[4];
    float* Y = (float*)d_out;

    const int points = in_sizes[0] / (64 * 3);   // B*N = 65536
    const int blocks = points / 64;              // 1024 (64 points per block)
    affine_linear_fused<<<blocks, 256, 0, stream>>>(X, J, A, Bm, C, Y);
}

// Round 4
// 205.786 us; speedup vs baseline: 1.0610x; 1.0610x over previous
//
#include <hip/hip_runtime.h>

typedef __bf16 bf16;
typedef bf16 bf16x8 __attribute__((ext_vector_type(8)));
typedef float f32x4 __attribute__((ext_vector_type(4)));
typedef unsigned int u32;

#define PTS 16          // points per block (4 per wave)
#define WREG 6144       // per-wave LDS region bytes
// Per-wave region phases (aliased, all same-wave ordered or barrier-protected):
//   phase 0 (stage): [0,6144)  J for 4 pts, identity copy via global_load_lds
//   phase 1 (T):     [0,4800)  12 rows x 400B (row = q*3+i); J read to regs first
//   phase 2 (Y):     [0,3072)  after barrier2, wave-private 16pts x 48 floats
// LDS 4*6144 = 24576 B/block -> 6 blocks/CU (24 waves/CU), VGPR target <= 85.
// Raw s_barrier + lgkmcnt(0)-only: ONE vmcnt(0) per block (J/X/W together).
// All bulk global traffic (J stage, Y out) is coalesced 16B/lane; only X (12B
// stride) and W (L2-broadcast) remain divergent.

__device__ __forceinline__ void gld_lds16(const void* g, void* l) {
    __builtin_amdgcn_global_load_lds(
        (const __attribute__((address_space(1))) u32*)g,
        (__attribute__((address_space(3))) u32*)l, 16, 0, 0);
}

__global__ __launch_bounds__(256, 6)
void affine_linear_fused(const float* __restrict__ X, const float* __restrict__ J,
                         const float* __restrict__ A, const float* __restrict__ Bm,
                         const float* __restrict__ C, float* __restrict__ Y)
{
    __shared__ __attribute__((aligned(128))) unsigned char lds[4 * WREG];

    const int tid  = threadIdx.x;
    const int wave = tid >> 6;
    const int lane = tid & 63;
    const int l16  = lane & 15;
    const int lq   = lane >> 4;       // quad 0..3
    const long bn0 = (long)blockIdx.x * PTS;

    unsigned char* wbase = &lds[wave * WREG];

    // ---- Phase 0a: J coalesced async stage (6 x 1024B = 6144B, identity copy) ----
    {
        const float* jg = J + (bn0 + wave * 4) * 384;
        #pragma unroll
        for (int t = 0; t < 6; ++t)
            gld_lds16(jg + t * 256 + lane * 4, wbase + t * 1024);
    }

    // ---- Phase 0b: X direct strided loads (issued now, drain at vmcnt(0)) ----
    float xv[4][3];
    {
        const float* xg = X + (bn0 + wave * 4) * 192 + lane * 3;
        #pragma unroll
        for (int q = 0; q < 4; ++q) {
            xv[q][0] = xg[q * 192 + 0];
            xv[q][1] = xg[q * 192 + 1];
            xv[q][2] = xg[q * 192 + 2];
        }
    }

    // ---- Phase 0c: W fragment loads (L2/L3-broadcast; converted after drain) ----
    // W[f,k]: f = wave*16+l16; k = kk*32 + lq*8 + j; kk<2:A, <4:Bm, else C
    const int f = wave * 16 + l16;
    f32x4 wlo[6], whi[6];
    #pragma unroll
    for (int kk = 0; kk < 6; ++kk) {
        const float* src = (kk < 2) ? A : (kk < 4) ? Bm : C;
        const f32x4* p4 = (const f32x4*)(src + f * 64 + (kk & 1) * 32 + lq * 8);
        wlo[kk] = p4[0];
        whi[kk] = p4[1];
    }

    // ONE drain: J stage (asm-opaque), X, W all complete.
    __asm__ volatile("s_waitcnt vmcnt(0)" ::: "memory");

    // ---- Convert W to bf16 fragments (frees half the W registers) ----
    bf16x8 wfrag[6];
    #pragma unroll
    for (int kk = 0; kk < 6; ++kk) {
        bf16x8 w;
        w[0] = (bf16)wlo[kk][0]; w[1] = (bf16)wlo[kk][1];
        w[2] = (bf16)wlo[kk][2]; w[3] = (bf16)wlo[kk][3];
        w[4] = (bf16)whi[kk][0]; w[5] = (bf16)whi[kk][1];
        w[6] = (bf16)whi[kk][2]; w[7] = (bf16)whi[kk][3];
        wfrag[kk] = w;
    }

    // ---- Per point: J from LDS -> terms -> T rows (safe in-order aliasing:
    //      T bytes for point q only overlap J bytes of points <= q) ----
    const float* jlds = (const float*)wbase;
    #pragma unroll
    for (int q = 0; q < 4; ++q) {
        const float* jp = jlds + q * 384 + lane * 6;
        float2 ja  = *(const float2*)(jp + 0);
        float2 jb  = *(const float2*)(jp + 2);
        float2 jc2 = *(const float2*)(jp + 4);
        float a1x = ja.x,  a2x = ja.y;
        float a1y = jb.x,  a2y = jb.y;
        float a1z = jc2.x, a2z = jc2.y;
        float xx = xv[q][0], xy = xv[q][1], xz = xv[q][2];

        float n1sq = a1x*a1x + a1y*a1y + a1z*a1z;
        float inv1 = __builtin_amdgcn_rsqf(fmaxf(n1sq, 1e-24f));  // == 1/max(sqrt,1e-12)
        float b1x = a1x*inv1, b1y = a1y*inv1, b1z = a1z*inv1;
        float dot = b1x*a2x + b1y*a2y + b1z*a2z;
        float ux = a2x - dot*b1x, uy = a2y - dot*b1y, uz = a2z - dot*b1z;
        float n2sq = ux*ux + uy*uy + uz*uz;
        float inv2 = __builtin_amdgcn_rsqf(fmaxf(n2sq, 1e-24f));
        float b2x = ux*inv2, b2y = uy*inv2, b2z = uz*inv2;
        float b3x = b1y*b2z - b1z*b2y;
        float b3y = b1z*b2x - b1x*b2z;
        float b3z = b1x*b2y - b1y*b2x;

        float rt0 = b1x*xx + b1y*xy + b1z*xz;
        float rt1 = b2x*xx + b2y*xy + b2z*xz;
        float rt2 = b3x*xx + b3y*xy + b3z*xz;

        float at0 = b1x*rt0 + b2x*rt1;
        float at1 = b1y*rt0 + b2y*rt1;
        float at2 = b1z*rt0 + b2z*rt1;
        float bt0 = b2x*rt0 - b1x*rt1;
        float bt1 = b2y*rt0 - b1y*rt1;
        float bt2 = b2z*rt0 - b1z*rt1;
        float ct0 = b3x*rt2, ct1 = b3y*rt2, ct2 = b3z*rt2;

        bf16* r0 = (bf16*)(wbase + (q*3 + 0) * 400);
        bf16* r1 = (bf16*)(wbase + (q*3 + 1) * 400);
        bf16* r2 = (bf16*)(wbase + (q*3 + 2) * 400);
        r0[lane] = (bf16)at0; r0[64+lane] = (bf16)bt0; r0[128+lane] = (bf16)ct0;
        r1[lane] = (bf16)at1; r1[64+lane] = (bf16)bt1; r1[128+lane] = (bf16)ct1;
        r2[lane] = (bf16)at2; r2[64+lane] = (bf16)bt2; r2[128+lane] = (bf16)ct2;
    }

    // barrier 1: publish T (lgkm-only; no vmem outstanding needs draining)
    __asm__ volatile("s_waitcnt lgkmcnt(0)" ::: "memory");
    __builtin_amdgcn_s_barrier();

    // ---- MFMA: D[m,f] = sum_k T[m,k] * W[f,k]; T row m = wv*12 + r ----
    const unsigned char* arow[3];
    #pragma unroll
    for (int mt = 0; mt < 3; ++mt) {
        int m  = mt * 16 + l16;
        int wv = m / 12;
        int r  = m - wv * 12;
        arow[mt] = &lds[wv * WREG + r * 400] + lq * 16;
    }
    f32x4 acc[3];
    #pragma unroll
    for (int mt = 0; mt < 3; ++mt) acc[mt] = (f32x4){0.f, 0.f, 0.f, 0.f};
    #pragma unroll
    for (int kk = 0; kk < 6; ++kk) {
        #pragma unroll
        for (int mt = 0; mt < 3; ++mt) {
            bf16x8 af = *(const bf16x8*)(arow[mt] + kk * 64);
            acc[mt] = __builtin_amdgcn_mfma_f32_16x16x32_bf16(af, wfrag[kk], acc[mt], 0, 0, 0);
        }
    }

    // barrier 2: all cross-wave T reads consumed; regions reusable.
    __asm__ volatile("s_waitcnt lgkmcnt(0)" ::: "memory");
    __builtin_amdgcn_s_barrier();

    // ---- Wave-private Y scatter: f-cols [16w,16w+16) => 48 floats per point ----
    float* yw = (float*)wbase;
    #pragma unroll
    for (int mt = 0; mt < 3; ++mt) {
        #pragma unroll
        for (int r = 0; r < 4; ++r) {
            int m  = mt * 16 + lq * 4 + r;
            int wv = m / 12;
            int rr = m - wv * 12;
            int q  = rr / 3;
            int i  = rr - q * 3;
            int p  = wv * 4 + q;
            yw[p * 48 + l16 * 3 + i] = acc[mt][r];
        }
    }

    // ---- Wave-private coalesced writeout: 16 chunks of 192 B ----
    const f32x4* ysrc = (const f32x4*)yw;
    #pragma unroll
    for (int v = 0; v < 3; ++v) {
        int vi = v * 64 + lane;           // 0..191
        int p  = vi / 12;
        int vo = vi - p * 12;
        f32x4* dst = (f32x4*)(Y + (bn0 + p) * 192 + wave * 48) + vo;
        *dst = ysrc[vi];
    }
}

extern "C" void kernel_launch(void* const* d_in, const int* in_sizes, int n_in,
                              void* d_out, int out_size, void* d_ws, size_t ws_size,
                              hipStream_t stream) {
    const float* X  = (const float*)d_in[0];
    const float* J  = (const float*)d_in[1];
    const float* A  = (const float*)d_in[2];
    const float* Bm = (const float*)d_in[3];
    const float* C  = (const float*)d_in[4];
    float* Y = (float*)d_out;

    const int points = in_sizes[0] / (64 * 3);   // B*N = 65536
    const int blocks = points / PTS;             // 4096
    affine_linear_fused<<<blocks, 256, 0, stream>>>(X, J, A, Bm, C, Y);
}